// Round 6
// baseline (349.080 us; speedup 1.0000x reference)
//
#include <hip/hip_runtime.h>

// B=4, T=1024, C=16, D=256, P=4096.  Float tensors fp32; x_mask u8; pos i32.
// ws: q[bc][t][d] bf16 32MB | k[bc][t][d] bf16 32MB | vt[bc][d][t] bf16 32MB
//     | wb[3][256][256] bf16 384KB | mbg[64][1024] f32 256KB

typedef __attribute__((ext_vector_type(8))) short short8_t;
typedef __attribute__((ext_vector_type(4))) short short4_t;
typedef __attribute__((ext_vector_type(8))) float float8_t;
typedef __attribute__((ext_vector_type(4))) float float4_t;
typedef __attribute__((ext_vector_type(16))) float float16_t;
typedef __attribute__((ext_vector_type(2))) float float2_t;
typedef __attribute__((ext_vector_type(2))) int int2_t;

__device__ __forceinline__ float b2f(short s) {
    union { unsigned int u; float f; } x;
    x.u = ((unsigned int)(unsigned short)s) << 16;
    return x.f;
}
__device__ __forceinline__ short f2bt(float f) {   // truncate: ample headroom here
    union { float f; unsigned int u; } x; x.f = f;
    return (short)(x.u >> 16);
}

// async global->LDS, 16B per lane, dest = wave-uniform base + lane*16
__device__ __forceinline__ void stage16(const short* g, short* l) {
    __builtin_amdgcn_global_load_lds(
        (const __attribute__((address_space(1))) unsigned int*)g,
        (__attribute__((address_space(3))) unsigned int*)l, 16, 0, 0);
}

// ---------------------------------------------------------------------------
// Kernel 0: weights fp32->bf16 + mask-bias table. 448 blocks x 256.
// ---------------------------------------------------------------------------
__global__ __launch_bounds__(256) void prep_kernel(
    const float* __restrict__ wq, const float* __restrict__ wk,
    const float* __restrict__ wv, const unsigned char* __restrict__ xmask,
    short* __restrict__ wb, float* __restrict__ mbg)
{
    if (blockIdx.x < 192) {
        int idx = blockIdx.x * 256 + threadIdx.x;
        int mat = idx >> 14, off = idx & 16383;
        const float* src = (mat == 0) ? wq : ((mat == 1) ? wk : wv);
        float4_t v = *(const float4_t*)(src + (long)off * 4);
        short4_t o;
#pragma unroll
        for (int j = 0; j < 4; j++) o[j] = f2bt(v[j]);
        *(short4_t*)(wb + (long)idx * 4) = o;
    } else {
        int idx = (blockIdx.x - 192) * 256 + threadIdx.x;   // 0..65535
        int bc = idx >> 10, t = idx & 1023;
        int b = bc >> 4, c = bc & 15;
        mbg[idx] = xmask[((long)b * 1024 + t) * 16 + c] ? -1e30f : 0.0f;
    }
}

// ---------------------------------------------------------------------------
// Kernel 1: MFMA QKV projection + rotary (unchanged).
// ---------------------------------------------------------------------------
__global__ __launch_bounds__(256) void qkv_mfma_kernel(
    const float* __restrict__ x, const int* __restrict__ pos,
    const float* __restrict__ pe, const short* __restrict__ wb,
    const float* __restrict__ bq, const float* __restrict__ bk,
    const float* __restrict__ bv,
    short* __restrict__ qo, short* __restrict__ ko, short* __restrict__ vt)
{
    __shared__ __align__(16) short xs[64 * 264];
    __shared__ __align__(16) short ys[18432];
    __shared__ int posb[64];

    const int tid = threadIdx.x;
    const int lane = tid & 63;
    const int wid = tid >> 6;
    const int bc = blockIdx.x >> 4;
    const int t0 = (blockIdx.x & 15) * 64;
    const int b = bc >> 4, c = bc & 15;
    const int row = lane & 15, quad = lane >> 4;
    const int odd = lane & 1;
    const int n0 = wid * 64;
    const long kvbase = (long)bc * 262144;

#pragma unroll
    for (int j = 0; j < 8; j++) {
        int idx = tid + j * 256;
        int r = idx >> 5, c8 = idx & 31;
        const float* xp = x + (((long)b * 1024 + t0 + r) * 16 + c) * 256 + c8 * 8;
        float4_t a = *(const float4_t*)xp;
        float4_t d = *(const float4_t*)(xp + 4);
        short8_t o;
        o[0] = f2bt(a.x); o[1] = f2bt(a.y); o[2] = f2bt(a.z); o[3] = f2bt(a.w);
        o[4] = f2bt(d.x); o[5] = f2bt(d.y); o[6] = f2bt(d.z); o[7] = f2bt(d.w);
        *(short8_t*)&xs[r * 264 + c8 * 8] = o;
    }
    if (tid < 64) posb[tid] = pos[((long)b * 1024 + t0 + tid) * 16 + c];
    __syncthreads();

#pragma unroll 1
    for (int mat = 0; mat < 3; mat++) {
        const short* W = wb + mat * 65536;
        float4_t acc[4][4];
#pragma unroll
        for (int mt = 0; mt < 4; mt++)
#pragma unroll
            for (int nt = 0; nt < 4; nt++) acc[mt][nt] = (float4_t){0.f, 0.f, 0.f, 0.f};

        short8_t Ac[4], Bc[4], An[4], Bn[4];
        auto loadA = [&](short8_t* A, int k0) {
#pragma unroll
            for (int mt = 0; mt < 4; mt++)
                A[mt] = *(const short8_t*)&xs[(mt * 16 + row) * 264 + k0 * 32 + quad * 8];
        };
        auto loadB = [&](short8_t* Bf, int k0) {
#pragma unroll
            for (int nt = 0; nt < 4; nt++)
                Bf[nt] = *(const short8_t*)(W + (n0 + nt * 16 + row) * 256 + k0 * 32 + quad * 8);
        };
        loadA(Ac, 0); loadB(Bc, 0);
#pragma unroll
        for (int k0 = 0; k0 < 8; k0++) {
            if (k0 < 7) { loadA(An, k0 + 1); loadB(Bn, k0 + 1); }
#pragma unroll
            for (int mt = 0; mt < 4; mt++)
#pragma unroll
                for (int nt = 0; nt < 4; nt++)
                    acc[mt][nt] = __builtin_amdgcn_mfma_f32_16x16x32_bf16(
                        Ac[mt], Bc[nt], acc[mt][nt], 0, 0, 0);
            if (k0 < 7) {
#pragma unroll
                for (int i = 0; i < 4; i++) { Ac[i] = An[i]; Bc[i] = Bn[i]; }
            }
        }

        const float* bias = (mat == 0) ? bq : ((mat == 1) ? bk : bv);
        float bs[4];
#pragma unroll
        for (int nt = 0; nt < 4; nt++) bs[nt] = bias[n0 + nt * 16 + row];
#pragma unroll
        for (int mt = 0; mt < 4; mt++)
#pragma unroll
            for (int nt = 0; nt < 4; nt++)
#pragma unroll
                for (int r = 0; r < 4; r++) acc[mt][nt][r] += bs[nt];

        if (mat < 2) {
#pragma unroll
            for (int mt = 0; mt < 4; mt++)
#pragma unroll
                for (int r = 0; r < 4; r++) {
                    int p = posb[mt * 16 + quad * 4 + r];
                    const float* pb = pe + (long)p * 256;
#pragma unroll
                    for (int nt = 0; nt < 4; nt++) {
                        int i = (n0 + nt * 16 + row) >> 1;
                        float2_t cs = *(const float2_t*)(pb + i * 2);
                        float v = acc[mt][nt][r];
                        float pr = __shfl_xor(v, 1);
                        acc[mt][nt][r] = v * cs.x + pr * (odd ? cs.y : -cs.y);
                    }
                }
        }

        __syncthreads();
        if (mat < 2) {
#pragma unroll
            for (int mt = 0; mt < 4; mt++)
#pragma unroll
                for (int nt = 0; nt < 4; nt++) {
                    int n = n0 + nt * 16 + row;
#pragma unroll
                    for (int r = 0; r < 4; r++)
                        ys[(mt * 16 + quad * 4 + r) * 264 + n] = f2bt(acc[mt][nt][r]);
                }
            __syncthreads();
            short* dst = ((mat == 0) ? qo : ko) + kvbase + (long)t0 * 256;
#pragma unroll
            for (int j = 0; j < 8; j++) {
                int idx = tid + j * 256;
                int r = idx >> 5, c8 = idx & 31;
                *(short8_t*)(dst + r * 256 + c8 * 8) = *(const short8_t*)&ys[r * 264 + c8 * 8];
            }
        } else {
#pragma unroll
            for (int mt = 0; mt < 4; mt++)
#pragma unroll
                for (int nt = 0; nt < 4; nt++) {
                    int n = n0 + nt * 16 + row;
                    short4_t o4;
#pragma unroll
                    for (int r = 0; r < 4; r++) o4[r] = f2bt(acc[mt][nt][r]);
                    *(short4_t*)&ys[n * 72 + mt * 16 + quad * 4] = o4;
                }
            __syncthreads();
#pragma unroll
            for (int j = 0; j < 8; j++) {
                int idx = tid + j * 256;
                int d = idx >> 3, t8 = idx & 7;
                *(short8_t*)(vt + kvbase + (long)d * 1024 + t0 + t8 * 8) =
                    *(const short8_t*)&ys[d * 72 + t8 * 8];
            }
        }
    }
}

// ---------------------------------------------------------------------------
// Kernel 2: flash attention, swapped-QK^T 32x32 form.
// 512 thr, 8 waves x 32 q-rows = 256 q/block, 256 blocks (1/CU).
// S^T = mfma_32x32x16(A=K, B=Q): lane owns q=lane&31 -> softmax lane-local
// (1 shfl_xor(32)); P transposed IN-REGISTER via 8 permlane32_swap; no PT
// LDS buffer at all.  K/V staging identical to r5 (quad-buffer, depth-2
// global_load_lds, counted vmcnt, ONE s_barrier per iter).
// LDS: K 4x16KB | V 4x16KB | mask 4KB | fac 1KB = 133KB -> 1 block/CU.
// ---------------------------------------------------------------------------
__global__ __launch_bounds__(512, 2) void attn_kernel(
    const short* __restrict__ qg, const short* __restrict__ kg,
    const short* __restrict__ vt, const float* __restrict__ mbg,
    const float* __restrict__ x,
    const float* __restrict__ lsg, const float* __restrict__ lng,
    const float* __restrict__ lnb, float* __restrict__ out)
{
    __shared__ __align__(16) short lds[68096];   // 136192 B
    // shorts: Ks[buf<4] @ buf*8192 (row r*256, 16B slot s holds gcol-slot s^(r&7))
    //         Vs[buf<4] @ 32768+buf*8192 (row d*32, 4 slots, slot s = gslot^((d>>1)&3))
    //         mbs f32   @ 65536 (1024 floats)
    //         fac f32   @ 67584 (8 waves x 32 floats, wave-private)

    const int tid = threadIdx.x;
    const int lane = tid & 63;
    const int wid = tid >> 6;
    // 256 blocks, 8 XCDs: chunked swizzle -> 32 consecutive bids per XCD
    const int bid = (blockIdx.x & 7) * 32 + (blockIdx.x >> 3);
    const int bc = bid >> 2;
    const int tq0 = (bid & 3) * 256;
    const int b = bc >> 4, c = bc & 15;
    const long kvbase = (long)bc * 262144;
    const int bcq = bc * 1024;
    const int col = lane & 31, hi = lane >> 5;   // col = q (and d/k row), hi = half
    float* mbsf = (float*)&lds[65536];
    float* facb = (float*)&lds[67584];

    auto stage = [&](int j, int buf) {
#pragma unroll
        for (int i = 0; i < 2; i++) {            // K tile: 32 rows x 512B
            int rp = (wid * 2 + i) * 2;
            int r = rp + (lane >> 5);
            int slot = lane & 31;
            const short* g = kg + kvbase + (long)(j * 32 + r) * 256 +
                             ((slot ^ (r & 7)) << 3);
            stage16(g, &lds[buf * 8192 + rp * 256]);
        }
#pragma unroll
        for (int i = 0; i < 2; i++) {            // V tile: 256 d-rows x 64B
            int db = (wid * 2 + i) * 16;
            int d = db + (lane >> 2);
            int slot = lane & 3;
            const short* g = vt + kvbase + (long)d * 1024 + j * 32 +
                             (((slot ^ ((d >> 1) & 3))) << 3);
            stage16(g, &lds[32768 + buf * 8192 + db * 32]);
        }
    };

    // ---- prologue: stage tiles 0,1; mask -> LDS; Q frags -> regs ----
    stage(0, 0);
    stage(1, 1);
#pragma unroll
    for (int i = tid; i < 1024; i += 512) mbsf[i] = mbg[bcq + i];
    // Q: lane holds q-row = col, d-halves per hi: aq[f] = Q[q][f*16+hi*8 ..+8)
    short8_t aq[16];
    {
        const short* qrow = qg + kvbase + (long)(tq0 + wid * 32 + col) * 256;
#pragma unroll
        for (int f = 0; f < 16; f++)
            aq[f] = *(const short8_t*)(qrow + f * 16 + hi * 8);
    }

    float16_t oacc[8];                 // O[q-pattern][d = nt*32+col], 128 f32
#pragma unroll
    for (int nt = 0; nt < 8; nt++)
#pragma unroll
        for (int i = 0; i < 16; i++) oacc[nt][i] = 0.f;
    float m = -__builtin_inff(), lsum = 0.f;

    const float scale = 0.0625f;
    const int ksw = col & 7;           // K row swizzle (16B-slot XOR)
    const int vsw = (col >> 1) & 3;    // V row swizzle

    asm volatile("s_waitcnt lgkmcnt(0)" ::: "memory");   // mbs ds_writes done

#pragma unroll 1
    for (int j = 0; j < 32; j++) {
        if (j < 30) {
            stage(j + 2, (j + 2) & 3);
            asm volatile("s_waitcnt vmcnt(8)" ::: "memory");  // tile j landed
        } else if (j == 30) {
            asm volatile("s_waitcnt vmcnt(4)" ::: "memory");
        } else {
            asm volatile("s_waitcnt vmcnt(0)" ::: "memory");
        }
        __builtin_amdgcn_s_barrier();        // tile j staged for all waves

        const short* Kb = &lds[(j & 3) * 8192];
        const short* Vb = &lds[32768 + (j & 3) * 8192];

        // ---- S^T = K Q^T : lane holds 16 k-rows x 1 q-col (q = col) ----
        float16_t s;
#pragma unroll
        for (int i = 0; i < 16; i++) s[i] = 0.f;
        __builtin_amdgcn_s_setprio(1);
#pragma unroll
        for (int f = 0; f < 16; f++) {
            short8_t kf = *(const short8_t*)
                &Kb[col * 256 + ((((f << 1) + hi) ^ ksw) << 3)];
            s = __builtin_amdgcn_mfma_f32_32x32x16_bf16(kf, aq[f], s, 0, 0, 0);
        }
        __builtin_amdgcn_s_setprio(0);

        // scale + mask bias; k-row of reg r = (r&3)+8*(r>>2)+4*hi
        float sv[16];
#pragma unroll
        for (int r = 0; r < 16; r++) {
            int kr = (r & 3) + 8 * (r >> 2) + 4 * hi;
            sv[r] = s[r] * scale + mbsf[j * 32 + kr];
        }
        // tile max (lane-local + cross-half)
        float tm = sv[0];
#pragma unroll
        for (int r = 1; r < 16; r++) tm = fmaxf(tm, sv[r]);
        tm = fmaxf(tm, __shfl_xor(tm, 32));
        if (!__all(tm - m <= 8.f)) {         // rescale (rare: defer-max)
            float nm = fmaxf(m, tm);
            float fac = __expf(m - nm);
            lsum *= fac; m = nm;
            facb[wid * 32 + col] = fac;      // both halves write same value
            float facr[16];
#pragma unroll
            for (int r = 0; r < 16; r++)
                facr[r] = facb[wid * 32 + ((r & 3) + 8 * (r >> 2) + 4 * hi)];
#pragma unroll
            for (int nt = 0; nt < 8; nt++)
#pragma unroll
                for (int r = 0; r < 16; r++) oacc[nt][r] *= facr[r];
        }
        // P = exp(S-m), accumulate partial row-sum (own half)
        float p[16];
#pragma unroll
        for (int r = 0; r < 16; r++) { p[r] = __expf(sv[r] - m); lsum += p[r]; }
        // pack bf16 pairs; w order: k = {0,1},{2,3},{8,9},{10,11},{16..},{24..}+4hi
        unsigned int w[8];
#pragma unroll
        for (int i = 0; i < 8; i++)
            w[i] = ((unsigned int)(unsigned short)f2bt(p[2 * i + 1]) << 16) |
                   (unsigned short)f2bt(p[2 * i]);
        // in-register transpose to PV A-frags via permlane32_swap
        int2_t q02 = __builtin_amdgcn_permlane32_swap((int)w[0], (int)w[2], false, false);
        int2_t q13 = __builtin_amdgcn_permlane32_swap((int)w[1], (int)w[3], false, false);
        int2_t q46 = __builtin_amdgcn_permlane32_swap((int)w[4], (int)w[6], false, false);
        int2_t q57 = __builtin_amdgcn_permlane32_swap((int)w[5], (int)w[7], false, false);
        short8_t pa1, pa2;
        {
            union { int i4[4]; short8_t s8; } u;
            u.i4[0] = q02.x; u.i4[1] = q13.x; u.i4[2] = q02.y; u.i4[3] = q13.y;
            pa1 = u.s8;
            u.i4[0] = q46.x; u.i4[1] = q57.x; u.i4[2] = q46.y; u.i4[3] = q57.y;
            pa2 = u.s8;
        }

        // ---- O += P V : C rows = q-pattern, cols d = nt*32+col ----
        __builtin_amdgcn_s_setprio(1);
#pragma unroll
        for (int nt = 0; nt < 8; nt++) {
            const short* vp = &Vb[(nt * 32 + col) * 32];
            short8_t v1 = *(const short8_t*)(vp + ((hi ^ vsw) << 3));
            short8_t v2 = *(const short8_t*)(vp + (((2 + hi) ^ vsw) << 3));
            oacc[nt] = __builtin_amdgcn_mfma_f32_32x32x16_bf16(pa1, v1, oacc[nt], 0, 0, 0);
            oacc[nt] = __builtin_amdgcn_mfma_f32_32x32x16_bf16(pa2, v2, oacc[nt], 0, 0, 0);
        }
        __builtin_amdgcn_s_setprio(0);
        // no end-of-iter barrier: nb=4 keeps the prefetch target 3 bufs
        // ahead of anything a (max-1-barrier-behind) wave still reads
    }

    // ---- epilogue: softmax norm; y = x + ls*o; LayerNorm; store ----
    lsum += __shfl_xor(lsum, 32);
    const int qt = tq0 + wid * 32 + col;
    float invq = (mbsf[qt] != 0.0f) ? 0.0f : (1.0f / lsum);
    facb[wid * 32 + col] = invq;             // redistribute per-q -> C pattern
    float invr[16];
#pragma unroll
    for (int r = 0; r < 16; r++)
        invr[r] = facb[wid * 32 + ((r & 3) + 8 * (r >> 2) + 4 * hi)];

    const long xbase = (((long)b * 1024 + tq0 + wid * 32) * 16 + c) * 256;
    float s1r[16], s2r[16];
#pragma unroll
    for (int r = 0; r < 16; r++) { s1r[r] = 0.f; s2r[r] = 0.f; }
#pragma unroll
    for (int nt = 0; nt < 8; nt++) {
        int d = nt * 32 + col;
        float lg = lsg[d];
#pragma unroll
        for (int r = 0; r < 16; r++) {
            int qr = (r & 3) + 8 * (r >> 2) + 4 * hi;
            float yy = x[xbase + (long)qr * 4096 + d] + lg * (oacc[nt][r] * invr[r]);
            oacc[nt][r] = yy;
            s1r[r] += yy; s2r[r] += yy * yy;
        }
    }
    float mu[16], rstd[16];
#pragma unroll
    for (int r = 0; r < 16; r++) {
        float a = s1r[r], bb = s2r[r];
#pragma unroll
        for (int o = 1; o < 32; o <<= 1) { a += __shfl_xor(a, o); bb += __shfl_xor(bb, o); }
        mu[r] = a * (1.f / 256.f);
        float var = bb * (1.f / 256.f) - mu[r] * mu[r];
        rstd[r] = rsqrtf(var + 1e-5f);
    }
#pragma unroll
    for (int nt = 0; nt < 8; nt++) {
        int d = nt * 32 + col;
        float g2 = lng[d], bb = lnb[d];
#pragma unroll
        for (int r = 0; r < 16; r++) {
            int qr = (r & 3) + 8 * (r >> 2) + 4 * hi;
            out[xbase + (long)qr * 4096 + d] = (oacc[nt][r] - mu[r]) * rstd[r] * g2 + bb;
        }
    }
}

// ---------------------------------------------------------------------------
extern "C" void kernel_launch(void* const* d_in, const int* in_sizes, int n_in,
                              void* d_out, int out_size, void* d_ws, size_t ws_size,
                              hipStream_t stream) {
    const float* x = (const float*)d_in[0];
    const unsigned char* xmask = (const unsigned char*)d_in[1];
    const int* pos = (const int*)d_in[2];
    const float* pe = (const float*)d_in[3];
    const float* wq = (const float*)d_in[4];
    const float* bq = (const float*)d_in[5];
    const float* wk = (const float*)d_in[6];
    const float* bk = (const float*)d_in[7];
    const float* wv = (const float*)d_in[8];
    const float* bv = (const float*)d_in[9];
    const float* lng = (const float*)d_in[10];
    const float* lnb = (const float*)d_in[11];
    const float* lsg = (const float*)d_in[12];
    float* out = (float*)d_out;

    short* qw = (short*)d_ws;              // 32MB
    short* kw = qw + 16777216;             // 32MB
    short* vtw = kw + 16777216;            // 32MB
    short* wbw = vtw + 16777216;           // 384KB
    float* mbg = (float*)(wbw + 196608);   // 256KB mask bias

    prep_kernel<<<448, 256, 0, stream>>>(wq, wk, wv, xmask, wbw, mbg);
    qkv_mfma_kernel<<<1024, 256, 0, stream>>>(x, pos, pe, wbw, bq, bk, bv,
                                              qw, kw, vtw);
    attn_kernel<<<256, 512, 0, stream>>>(qw, kw, vtw, mbg, x, lsg, lng, lnb, out);
}

// Round 7
// 347.305 us; speedup vs baseline: 1.0051x; 1.0051x over previous
//
#include <hip/hip_runtime.h>

// B=4, T=1024, C=16, D=256, P=4096.  Float tensors fp32; x_mask u8; pos i32.
// ws: q[bc][t][d] bf16 32MB | k[bc][t][d] bf16 32MB | vt[bc][d][t] bf16 32MB
//     | wb[3][256][256] bf16 384KB | mbg[64][1024] f32 256KB

typedef __attribute__((ext_vector_type(8))) short short8_t;
typedef __attribute__((ext_vector_type(4))) short short4_t;
typedef __attribute__((ext_vector_type(8))) float float8_t;
typedef __attribute__((ext_vector_type(4))) float float4_t;
typedef __attribute__((ext_vector_type(16))) float float16_t;
typedef __attribute__((ext_vector_type(2))) float float2_t;
typedef __attribute__((ext_vector_type(2))) int int2_t;

__device__ __forceinline__ float b2f(short s) {
    union { unsigned int u; float f; } x;
    x.u = ((unsigned int)(unsigned short)s) << 16;
    return x.f;
}
__device__ __forceinline__ short f2bt(float f) {   // truncate: ample headroom here
    union { float f; unsigned int u; } x; x.f = f;
    return (short)(x.u >> 16);
}

// async global->LDS, 16B per lane, dest = wave-uniform base + lane*16
__device__ __forceinline__ void stage16(const short* g, short* l) {
    __builtin_amdgcn_global_load_lds(
        (const __attribute__((address_space(1))) unsigned int*)g,
        (__attribute__((address_space(3))) unsigned int*)l, 16, 0, 0);
}

// ---------------------------------------------------------------------------
// Kernel 0: weights fp32->bf16 + mask-bias table. 448 blocks x 256.
// ---------------------------------------------------------------------------
__global__ __launch_bounds__(256) void prep_kernel(
    const float* __restrict__ wq, const float* __restrict__ wk,
    const float* __restrict__ wv, const unsigned char* __restrict__ xmask,
    short* __restrict__ wb, float* __restrict__ mbg)
{
    if (blockIdx.x < 192) {
        int idx = blockIdx.x * 256 + threadIdx.x;
        int mat = idx >> 14, off = idx & 16383;
        const float* src = (mat == 0) ? wq : ((mat == 1) ? wk : wv);
        float4_t v = *(const float4_t*)(src + (long)off * 4);
        short4_t o;
#pragma unroll
        for (int j = 0; j < 4; j++) o[j] = f2bt(v[j]);
        *(short4_t*)(wb + (long)idx * 4) = o;
    } else {
        int idx = (blockIdx.x - 192) * 256 + threadIdx.x;   // 0..65535
        int bc = idx >> 10, t = idx & 1023;
        int b = bc >> 4, c = bc & 15;
        mbg[idx] = xmask[((long)b * 1024 + t) * 16 + c] ? -1e30f : 0.0f;
    }
}

// ---------------------------------------------------------------------------
// Kernel 1: MFMA QKV projection + rotary (unchanged).
// ---------------------------------------------------------------------------
__global__ __launch_bounds__(256) void qkv_mfma_kernel(
    const float* __restrict__ x, const int* __restrict__ pos,
    const float* __restrict__ pe, const short* __restrict__ wb,
    const float* __restrict__ bq, const float* __restrict__ bk,
    const float* __restrict__ bv,
    short* __restrict__ qo, short* __restrict__ ko, short* __restrict__ vt)
{
    __shared__ __align__(16) short xs[64 * 264];
    __shared__ __align__(16) short ys[18432];
    __shared__ int posb[64];

    const int tid = threadIdx.x;
    const int lane = tid & 63;
    const int wid = tid >> 6;
    const int bc = blockIdx.x >> 4;
    const int t0 = (blockIdx.x & 15) * 64;
    const int b = bc >> 4, c = bc & 15;
    const int row = lane & 15, quad = lane >> 4;
    const int odd = lane & 1;
    const int n0 = wid * 64;
    const long kvbase = (long)bc * 262144;

#pragma unroll
    for (int j = 0; j < 8; j++) {
        int idx = tid + j * 256;
        int r = idx >> 5, c8 = idx & 31;
        const float* xp = x + (((long)b * 1024 + t0 + r) * 16 + c) * 256 + c8 * 8;
        float4_t a = *(const float4_t*)xp;
        float4_t d = *(const float4_t*)(xp + 4);
        short8_t o;
        o[0] = f2bt(a.x); o[1] = f2bt(a.y); o[2] = f2bt(a.z); o[3] = f2bt(a.w);
        o[4] = f2bt(d.x); o[5] = f2bt(d.y); o[6] = f2bt(d.z); o[7] = f2bt(d.w);
        *(short8_t*)&xs[r * 264 + c8 * 8] = o;
    }
    if (tid < 64) posb[tid] = pos[((long)b * 1024 + t0 + tid) * 16 + c];
    __syncthreads();

#pragma unroll 1
    for (int mat = 0; mat < 3; mat++) {
        const short* W = wb + mat * 65536;
        float4_t acc[4][4];
#pragma unroll
        for (int mt = 0; mt < 4; mt++)
#pragma unroll
            for (int nt = 0; nt < 4; nt++) acc[mt][nt] = (float4_t){0.f, 0.f, 0.f, 0.f};

        short8_t Ac[4], Bc[4], An[4], Bn[4];
        auto loadA = [&](short8_t* A, int k0) {
#pragma unroll
            for (int mt = 0; mt < 4; mt++)
                A[mt] = *(const short8_t*)&xs[(mt * 16 + row) * 264 + k0 * 32 + quad * 8];
        };
        auto loadB = [&](short8_t* Bf, int k0) {
#pragma unroll
            for (int nt = 0; nt < 4; nt++)
                Bf[nt] = *(const short8_t*)(W + (n0 + nt * 16 + row) * 256 + k0 * 32 + quad * 8);
        };
        loadA(Ac, 0); loadB(Bc, 0);
#pragma unroll
        for (int k0 = 0; k0 < 8; k0++) {
            if (k0 < 7) { loadA(An, k0 + 1); loadB(Bn, k0 + 1); }
#pragma unroll
            for (int mt = 0; mt < 4; mt++)
#pragma unroll
                for (int nt = 0; nt < 4; nt++)
                    acc[mt][nt] = __builtin_amdgcn_mfma_f32_16x16x32_bf16(
                        Ac[mt], Bc[nt], acc[mt][nt], 0, 0, 0);
            if (k0 < 7) {
#pragma unroll
                for (int i = 0; i < 4; i++) { Ac[i] = An[i]; Bc[i] = Bn[i]; }
            }
        }

        const float* bias = (mat == 0) ? bq : ((mat == 1) ? bk : bv);
        float bs[4];
#pragma unroll
        for (int nt = 0; nt < 4; nt++) bs[nt] = bias[n0 + nt * 16 + row];
#pragma unroll
        for (int mt = 0; mt < 4; mt++)
#pragma unroll
            for (int nt = 0; nt < 4; nt++)
#pragma unroll
                for (int r = 0; r < 4; r++) acc[mt][nt][r] += bs[nt];

        if (mat < 2) {
#pragma unroll
            for (int mt = 0; mt < 4; mt++)
#pragma unroll
                for (int r = 0; r < 4; r++) {
                    int p = posb[mt * 16 + quad * 4 + r];
                    const float* pb = pe + (long)p * 256;
#pragma unroll
                    for (int nt = 0; nt < 4; nt++) {
                        int i = (n0 + nt * 16 + row) >> 1;
                        float2_t cs = *(const float2_t*)(pb + i * 2);
                        float v = acc[mt][nt][r];
                        float pr = __shfl_xor(v, 1);
                        acc[mt][nt][r] = v * cs.x + pr * (odd ? cs.y : -cs.y);
                    }
                }
        }

        __syncthreads();
        if (mat < 2) {
#pragma unroll
            for (int mt = 0; mt < 4; mt++)
#pragma unroll
                for (int nt = 0; nt < 4; nt++) {
                    int n = n0 + nt * 16 + row;
#pragma unroll
                    for (int r = 0; r < 4; r++)
                        ys[(mt * 16 + quad * 4 + r) * 264 + n] = f2bt(acc[mt][nt][r]);
                }
            __syncthreads();
            short* dst = ((mat == 0) ? qo : ko) + kvbase + (long)t0 * 256;
#pragma unroll
            for (int j = 0; j < 8; j++) {
                int idx = tid + j * 256;
                int r = idx >> 5, c8 = idx & 31;
                *(short8_t*)(dst + r * 256 + c8 * 8) = *(const short8_t*)&ys[r * 264 + c8 * 8];
            }
        } else {
#pragma unroll
            for (int mt = 0; mt < 4; mt++)
#pragma unroll
                for (int nt = 0; nt < 4; nt++) {
                    int n = n0 + nt * 16 + row;
                    short4_t o4;
#pragma unroll
                    for (int r = 0; r < 4; r++) o4[r] = f2bt(acc[mt][nt][r]);
                    *(short4_t*)&ys[n * 72 + mt * 16 + quad * 4] = o4;
                }
            __syncthreads();
#pragma unroll
            for (int j = 0; j < 8; j++) {
                int idx = tid + j * 256;
                int d = idx >> 3, t8 = idx & 7;
                *(short8_t*)(vt + kvbase + (long)d * 1024 + t0 + t8 * 8) =
                    *(const short8_t*)&ys[d * 72 + t8 * 8];
            }
        }
    }
}

// ---------------------------------------------------------------------------
// Kernel 2: flash attention, swapped-QK^T 32x32 form.
// 512 thr, 8 waves x 32 q-rows = 256 q/block, 256 blocks (1/CU).
// S^T = mfma_32x32x16(A=K, B=Q): lane owns q=lane&31 -> softmax lane-local;
// P transposed IN-REGISTER via permlane32_swap; no PT LDS buffer.
// K/V staging: quad-buffer, depth-2 global_load_lds, counted vmcnt, ONE
// s_barrier per iter.  launch_bounds(512,1): occupancy is LDS-capped at
// 1 block/CU (8 waves) regardless of regs <= ~1000, so DO NOT cap the
// allocator at 256 (r6's (512,2) cap spilled ~72MB/dispatch to scratch).
// LDS: K 4x16KB | V 4x16KB | mask 4KB | fac 1KB = 133KB -> 1 block/CU.
// ---------------------------------------------------------------------------
__global__ __launch_bounds__(512, 1) void attn_kernel(
    const short* __restrict__ qg, const short* __restrict__ kg,
    const short* __restrict__ vt, const float* __restrict__ mbg,
    const float* __restrict__ x,
    const float* __restrict__ lsg, const float* __restrict__ lng,
    const float* __restrict__ lnb, float* __restrict__ out)
{
    __shared__ __align__(16) short lds[68096];   // 136192 B
    // shorts: Ks[buf<4] @ buf*8192 (row r*256, 16B slot s holds gcol-slot s^(r&7))
    //         Vs[buf<4] @ 32768+buf*8192 (row d*32, 4 slots, slot s = gslot^((d>>1)&3))
    //         mbs f32   @ 65536 (1024 floats)
    //         fac f32   @ 67584 (8 waves x 32 floats, wave-private)

    const int tid = threadIdx.x;
    const int lane = tid & 63;
    const int wid = tid >> 6;
    // 256 blocks, 8 XCDs: chunked swizzle -> 32 consecutive bids per XCD
    const int bid = (blockIdx.x & 7) * 32 + (blockIdx.x >> 3);
    const int bc = bid >> 2;
    const int tq0 = (bid & 3) * 256;
    const int b = bc >> 4, c = bc & 15;
    const long kvbase = (long)bc * 262144;
    const int bcq = bc * 1024;
    const int col = lane & 31, hi = lane >> 5;   // col = q (and d/k row), hi = half
    float* mbsf = (float*)&lds[65536];
    float* facb = (float*)&lds[67584];

    auto stage = [&](int j, int buf) {
#pragma unroll
        for (int i = 0; i < 2; i++) {            // K tile: 32 rows x 512B
            int rp = (wid * 2 + i) * 2;
            int r = rp + (lane >> 5);
            int slot = lane & 31;
            const short* g = kg + kvbase + (long)(j * 32 + r) * 256 +
                             ((slot ^ (r & 7)) << 3);
            stage16(g, &lds[buf * 8192 + rp * 256]);
        }
#pragma unroll
        for (int i = 0; i < 2; i++) {            // V tile: 256 d-rows x 64B
            int db = (wid * 2 + i) * 16;
            int d = db + (lane >> 2);
            int slot = lane & 3;
            const short* g = vt + kvbase + (long)d * 1024 + j * 32 +
                             (((slot ^ ((d >> 1) & 3))) << 3);
            stage16(g, &lds[32768 + buf * 8192 + db * 32]);
        }
    };

    // ---- prologue: stage tiles 0,1; mask -> LDS; Q frags -> regs ----
    stage(0, 0);
    stage(1, 1);
#pragma unroll
    for (int i = tid; i < 1024; i += 512) mbsf[i] = mbg[bcq + i];
    // Q: lane holds q-row = col, d-halves per hi: aq[f] = Q[q][f*16+hi*8 ..+8)
    short8_t aq[16];
    {
        const short* qrow = qg + kvbase + (long)(tq0 + wid * 32 + col) * 256;
#pragma unroll
        for (int f = 0; f < 16; f++)
            aq[f] = *(const short8_t*)(qrow + f * 16 + hi * 8);
    }

    float16_t oacc[8];                 // O[q-pattern][d = nt*32+col], 128 f32
#pragma unroll
    for (int nt = 0; nt < 8; nt++)
#pragma unroll
        for (int i = 0; i < 16; i++) oacc[nt][i] = 0.f;
    float m = -__builtin_inff(), lsum = 0.f;

    const float scale = 0.0625f;
    const int ksw = col & 7;           // K row swizzle (16B-slot XOR)
    const int vsw = (col >> 1) & 3;    // V row swizzle

    asm volatile("s_waitcnt lgkmcnt(0)" ::: "memory");   // mbs ds_writes done

#pragma unroll 1
    for (int j = 0; j < 32; j++) {
        if (j < 30) {
            stage(j + 2, (j + 2) & 3);
            asm volatile("s_waitcnt vmcnt(8)" ::: "memory");  // tile j landed
        } else if (j == 30) {
            asm volatile("s_waitcnt vmcnt(4)" ::: "memory");
        } else {
            asm volatile("s_waitcnt vmcnt(0)" ::: "memory");
        }
        __builtin_amdgcn_s_barrier();        // tile j staged for all waves

        const short* Kb = &lds[(j & 3) * 8192];
        const short* Vb = &lds[32768 + (j & 3) * 8192];

        // ---- S^T = K Q^T : lane holds 16 k-rows x 1 q-col (q = col) ----
        float16_t s;
#pragma unroll
        for (int i = 0; i < 16; i++) s[i] = 0.f;
        __builtin_amdgcn_s_setprio(1);
#pragma unroll
        for (int f = 0; f < 16; f++) {
            short8_t kf = *(const short8_t*)
                &Kb[col * 256 + ((((f << 1) + hi) ^ ksw) << 3)];
            s = __builtin_amdgcn_mfma_f32_32x32x16_bf16(kf, aq[f], s, 0, 0, 0);
        }
        __builtin_amdgcn_s_setprio(0);

        // scale + mask bias; k-row of reg r = (r&3)+8*(r>>2)+4*hi
        // kr groups of 4 are contiguous: {0..3},{8..11},{16..19},{24..27} +4hi
        float4_t mb4[4];
#pragma unroll
        for (int g4 = 0; g4 < 4; g4++)
            mb4[g4] = *(const float4_t*)&mbsf[j * 32 + 4 * hi + 8 * g4];
        float sv[16];
#pragma unroll
        for (int r = 0; r < 16; r++)
            sv[r] = s[r] * scale + mb4[r >> 2][r & 3];
        // tile max (lane-local + cross-half)
        float tm = sv[0];
#pragma unroll
        for (int r = 1; r < 16; r++) tm = fmaxf(tm, sv[r]);
        tm = fmaxf(tm, __shfl_xor(tm, 32));
        if (!__all(tm - m <= 8.f)) {         // rescale (rare: defer-max)
            float nm = fmaxf(m, tm);
            float fac = __expf(m - nm);
            lsum *= fac; m = nm;
            facb[wid * 32 + col] = fac;      // both halves write same value
            float facr[16];
#pragma unroll
            for (int r = 0; r < 16; r++)
                facr[r] = facb[wid * 32 + ((r & 3) + 8 * (r >> 2) + 4 * hi)];
#pragma unroll
            for (int nt = 0; nt < 8; nt++)
#pragma unroll
                for (int r = 0; r < 16; r++) oacc[nt][r] *= facr[r];
        }
        // P = exp(S-m), accumulate partial row-sum (own half)
        float p[16];
#pragma unroll
        for (int r = 0; r < 16; r++) { p[r] = __expf(sv[r] - m); lsum += p[r]; }
        // pack bf16 pairs; w order: k = {0,1},{2,3},{8,9},{10,11},{16..},{24..}+4hi
        unsigned int w[8];
#pragma unroll
        for (int i = 0; i < 8; i++)
            w[i] = ((unsigned int)(unsigned short)f2bt(p[2 * i + 1]) << 16) |
                   (unsigned short)f2bt(p[2 * i]);
        // in-register transpose to PV A-frags via permlane32_swap
        int2_t q02 = __builtin_amdgcn_permlane32_swap((int)w[0], (int)w[2], false, false);
        int2_t q13 = __builtin_amdgcn_permlane32_swap((int)w[1], (int)w[3], false, false);
        int2_t q46 = __builtin_amdgcn_permlane32_swap((int)w[4], (int)w[6], false, false);
        int2_t q57 = __builtin_amdgcn_permlane32_swap((int)w[5], (int)w[7], false, false);
        short8_t pa1, pa2;
        {
            union { int i4[4]; short8_t s8; } u;
            u.i4[0] = q02.x; u.i4[1] = q13.x; u.i4[2] = q02.y; u.i4[3] = q13.y;
            pa1 = u.s8;
            u.i4[0] = q46.x; u.i4[1] = q57.x; u.i4[2] = q46.y; u.i4[3] = q57.y;
            pa2 = u.s8;
        }

        // ---- O += P V : C rows = q-pattern, cols d = nt*32+col ----
        __builtin_amdgcn_s_setprio(1);
#pragma unroll
        for (int nt = 0; nt < 8; nt++) {
            const short* vp = &Vb[(nt * 32 + col) * 32];
            short8_t v1 = *(const short8_t*)(vp + ((hi ^ vsw) << 3));
            short8_t v2 = *(const short8_t*)(vp + (((2 + hi) ^ vsw) << 3));
            oacc[nt] = __builtin_amdgcn_mfma_f32_32x32x16_bf16(pa1, v1, oacc[nt], 0, 0, 0);
            oacc[nt] = __builtin_amdgcn_mfma_f32_32x32x16_bf16(pa2, v2, oacc[nt], 0, 0, 0);
        }
        __builtin_amdgcn_s_setprio(0);
        // no end-of-iter barrier: nb=4 keeps the prefetch target 3 bufs
        // ahead of anything a (max-1-barrier-behind) wave still reads
    }

    // ---- epilogue: softmax norm; y = x + ls*o; LayerNorm; store ----
    lsum += __shfl_xor(lsum, 32);
    const int qt = tq0 + wid * 32 + col;
    float invq = (mbsf[qt] != 0.0f) ? 0.0f : (1.0f / lsum);
    facb[wid * 32 + col] = invq;             // redistribute per-q -> C pattern
    float invr[16];
#pragma unroll
    for (int r = 0; r < 16; r++)
        invr[r] = facb[wid * 32 + ((r & 3) + 8 * (r >> 2) + 4 * hi)];

    const long xbase = (((long)b * 1024 + tq0 + wid * 32) * 16 + c) * 256;
    float s1r[16], s2r[16];
#pragma unroll
    for (int r = 0; r < 16; r++) { s1r[r] = 0.f; s2r[r] = 0.f; }
#pragma unroll
    for (int nt = 0; nt < 8; nt++) {
        int d = nt * 32 + col;
        float lg = lsg[d];
#pragma unroll
        for (int r = 0; r < 16; r++) {
            int qr = (r & 3) + 8 * (r >> 2) + 4 * hi;
            float yy = x[xbase + (long)qr * 4096 + d] + lg * (oacc[nt][r] * invr[r]);
            oacc[nt][r] = yy;
            s1r[r] += yy; s2r[r] += yy * yy;
        }
    }
    float mu[16], rstd[16];
#pragma unroll
    for (int r = 0; r < 16; r++) {
        float a = s1r[r], bb = s2r[r];
#pragma unroll
        for (int o = 1; o < 32; o <<= 1) { a += __shfl_xor(a, o); bb += __shfl_xor(bb, o); }
        mu[r] = a * (1.f / 256.f);
        float var = bb * (1.f / 256.f) - mu[r] * mu[r];
        rstd[r] = rsqrtf(var + 1e-5f);
    }
#pragma unroll
    for (int nt = 0; nt < 8; nt++) {
        int d = nt * 32 + col;
        float g2 = lng[d], bb = lnb[d];
#pragma unroll
        for (int r = 0; r < 16; r++) {
            int qr = (r & 3) + 8 * (r >> 2) + 4 * hi;
            out[xbase + (long)qr * 4096 + d] = (oacc[nt][r] - mu[r]) * rstd[r] * g2 + bb;
        }
    }
}

// ---------------------------------------------------------------------------
extern "C" void kernel_launch(void* const* d_in, const int* in_sizes, int n_in,
                              void* d_out, int out_size, void* d_ws, size_t ws_size,
                              hipStream_t stream) {
    const float* x = (const float*)d_in[0];
    const unsigned char* xmask = (const unsigned char*)d_in[1];
    const int* pos = (const int*)d_in[2];
    const float* pe = (const float*)d_in[3];
    const float* wq = (const float*)d_in[4];
    const float* bq = (const float*)d_in[5];
    const float* wk = (const float*)d_in[6];
    const float* bk = (const float*)d_in[7];
    const float* wv = (const float*)d_in[8];
    const float* bv = (const float*)d_in[9];
    const float* lng = (const float*)d_in[10];
    const float* lnb = (const float*)d_in[11];
    const float* lsg = (const float*)d_in[12];
    float* out = (float*)d_out;

    short* qw = (short*)d_ws;              // 32MB
    short* kw = qw + 16777216;             // 32MB
    short* vtw = kw + 16777216;            // 32MB
    short* wbw = vtw + 16777216;           // 384KB
    float* mbg = (float*)(wbw + 196608);   // 256KB mask bias

    prep_kernel<<<448, 256, 0, stream>>>(wq, wk, wv, xmask, wbw, mbg);
    qkv_mfma_kernel<<<1024, 256, 0, stream>>>(x, pos, pe, wbw, bq, bk, bv,
                                              qw, kw, vtw);
    attn_kernel<<<256, 512, 0, stream>>>(qw, kw, vtw, mbg, x, lsg, lng, lnb, out);
}